// Round 2
// baseline (440.516 us; speedup 1.0000x reference)
//
#include <hip/hip_runtime.h>

// ---------------------------------------------------------------------------
// GraphSAGE 2-layer hetero (R=2) + edge dot scorer.  Round 10:
//  * agg1: half-wave per edge -> 2 edges per load instruction (32 lanes x
//    8B uint2 per row), unroll 8 loads = 16 edges in flight (was 8 with
//    twice the load instructions). csr indices prefetched 16-deep via
//    readfirstlane, cross-half __shfl_xor(32) reduction.
//  * agg2: quarter-wave per edge -> 4 edges per load instruction (16 lanes
//    x 8B per 128B row), 16 edges in flight per iter, shfl_xor(16|32)
//    reduce. (agg kernels are latency-bound on the L2-miss path: HBM 38%,
//    VALU 29%, nothing saturated -> raise MLP per instruction slot.)
//  * layer-2 GEMM: 3 outputs (z2,t0,t1) fused into ONE kernel -> h1b read
//    once (12.8MB) instead of 3x (38.4MB), -2 launches.
//  * Layer 1 stays aggregate-first + fused 3-matmul GEMM (round 9).
//  * CSR build (BW=128 buckets) unchanged.
// ---------------------------------------------------------------------------

#define BW 128            // nodes per radix bucket (pow2)
#define NBK_MAX 1024
#define EPB 8192          // edges per block in radix passes

typedef __attribute__((ext_vector_type(8))) short bf16x8;
typedef __attribute__((ext_vector_type(4))) float floatx4;

__device__ __forceinline__ unsigned short f2bf(float f) {
    unsigned u = __float_as_uint(f);
    unsigned r = u + 0x7FFFu + ((u >> 16) & 1u);
    return (unsigned short)(r >> 16);
}
__device__ __forceinline__ unsigned pack2(float a, float b) {
    return (unsigned)f2bf(a) | ((unsigned)f2bf(b) << 16);
}
__device__ __forceinline__ float bflo(unsigned v) { return __uint_as_float(v << 16); }
__device__ __forceinline__ float bfhi(unsigned v) { return __uint_as_float(v & 0xFFFF0000u); }
#define RFL(x) __builtin_amdgcn_readfirstlane(x)

// ---- radix pass A: per-(r,bucket) counts --------------------------------
__global__ __launch_bounds__(256) void
bucket_count_kernel(const int* __restrict__ edges, int* __restrict__ bcnt,
                    int NBK, int E)
{
    __shared__ int cnt[2 * NBK_MAX];
    const int rbT = 2 * NBK;
    const int t = threadIdx.x;
    for (int k = t; k < rbT; k += 256) cnt[k] = 0;
    __syncthreads();
    long long start = (long long)blockIdx.x * EPB;
    long long twoE = 2LL * E;
    for (int u = 0; u < EPB / 256; ++u) {
        long long idx = start + u * 256 + t;
        if (idx < twoE) {
            int r = idx >= E;
            int e = (int)(idx - (long long)r * E);
            int d = edges[(size_t)r * 2 * E + E + e];
            atomicAdd(&cnt[r * NBK + (d >> 7)], 1);
        }
    }
    __syncthreads();
    for (int k = t; k < rbT; k += 256)
        if (cnt[k]) atomicAdd(&bcnt[k], cnt[k]);
}

// ---- radix pass B: exclusive scan of bucket counts ----------------------
__global__ __launch_bounds__(1024) void
bucket_scan_kernel(const int* __restrict__ bcnt, int* __restrict__ bko,
                   int rbT, int twoE)
{
    __shared__ int sm[1024];
    int t = threadIdx.x;
    int v = (t < rbT) ? bcnt[t] : 0;
    sm[t] = v;
    __syncthreads();
    for (int s = 1; s < 1024; s <<= 1) {
        int u = (t >= s) ? sm[t - s] : 0;
        __syncthreads();
        sm[t] += u;
        __syncthreads();
    }
    if (t < rbT) bko[t] = sm[t] - v;
    if (t == 0) bko[rbT] = twoE;
}

// ---- radix pass C: partition into bucket-grouped (src,dst) pairs --------
__global__ __launch_bounds__(256) void
partition_kernel(const int* __restrict__ edges, const int* __restrict__ bko,
                 int* __restrict__ gcur, uint2* __restrict__ staging,
                 int NBK, int E)
{
    __shared__ int cnt[2 * NBK_MAX];
    __shared__ int base[2 * NBK_MAX];
    const int rbT = 2 * NBK;
    const int t = threadIdx.x;
    for (int k = t; k < rbT; k += 256) cnt[k] = 0;
    __syncthreads();
    long long start = (long long)blockIdx.x * EPB;
    long long twoE = 2LL * E;
    for (int u = 0; u < EPB / 256; ++u) {
        long long idx = start + u * 256 + t;
        if (idx < twoE) {
            int r = idx >= E;
            int e = (int)(idx - (long long)r * E);
            int d = edges[(size_t)r * 2 * E + E + e];
            atomicAdd(&cnt[r * NBK + (d >> 7)], 1);
        }
    }
    __syncthreads();
    for (int k = t; k < rbT; k += 256) {
        int c0 = cnt[k];
        if (c0) base[k] = bko[k] + atomicAdd(&gcur[k], c0);
        cnt[k] = 0;
    }
    __syncthreads();
    for (int u = 0; u < EPB / 256; ++u) {
        long long idx = start + u * 256 + t;
        if (idx < twoE) {
            int r = idx >= E;
            int e = (int)(idx - (long long)r * E);
            int s = edges[(size_t)r * 2 * E + e];
            int d = edges[(size_t)r * 2 * E + E + e];
            int rb = r * NBK + (d >> 7);
            int pos = atomicAdd(&cnt[rb], 1);
            staging[(size_t)base[rb] + pos] = make_uint2((unsigned)s, (unsigned)d);
        }
    }
}

// ---- radix pass D: per-bucket node hist/scan -> off[] and csr[] ----------
__global__ __launch_bounds__(256) void
bucket_csr_kernel(const uint2* __restrict__ staging, const int* __restrict__ bko,
                  int* __restrict__ csr, int* __restrict__ off,
                  int NBK, int N)
{
    __shared__ int hist[BW], excl[BW], cur[BW], sc[BW];
    const int rb = blockIdx.x;
    const int r = rb / NBK;
    const int b = rb % NBK;
    const int node0 = b * BW;
    const int nn = min(BW, N - node0);
    const int cbase = bko[rb];
    const int c = bko[rb + 1] - cbase;
    const int t = threadIdx.x;

    if (t < BW) { hist[t] = 0; cur[t] = 0; }
    __syncthreads();
    for (int k = t; k < c; k += 256)
        atomicAdd(&hist[(int)staging[(size_t)cbase + k].y - node0], 1);
    __syncthreads();
    if (t < BW) sc[t] = hist[t];
    __syncthreads();
    for (int s = 1; s < BW; s <<= 1) {
        int v = (t < BW && t >= s) ? sc[t - s] : 0;
        __syncthreads();
        if (t < BW) sc[t] += v;
        __syncthreads();
    }
    if (t < BW) excl[t] = sc[t] - hist[t];
    if (t < nn) off[(size_t)r * N + node0 + t] = cbase + excl[t];
    __syncthreads();
    for (int k = t; k < c; k += 256) {
        uint2 pr = staging[(size_t)cbase + k];
        int l = (int)pr.y - node0;
        int pos = atomicAdd(&cur[l], 1);
        csr[(size_t)cbase + excl[l] + pos] = (int)pr.x;
    }
}

// ---- f32 -> bf16 --------------------------------------------------------
__global__ void cvt_kernel(const float* __restrict__ in,
                           unsigned short* __restrict__ o, int n4)
{
    int t = blockIdx.x * blockDim.x + threadIdx.x;
    if (t >= n4) return;
    float4 v = ((const float4*)in)[t];
    ushort4 r;
    r.x = f2bf(v.x); r.y = f2bf(v.y); r.z = f2bf(v.z); r.w = f2bf(v.w);
    ((ushort4*)o)[t] = r;
}

// ---- weight prep: combined-Wself / Wn -> bf16 W^T rows, biases ----------
__global__ void prep_kernel(const float* __restrict__ Ws1, const float* __restrict__ Wn1,
                            const float* __restrict__ b1,
                            const float* __restrict__ Ws2, const float* __restrict__ Wn2,
                            const float* __restrict__ b2,
                            unsigned short* __restrict__ WT1z, unsigned short* __restrict__ WT1a,
                            unsigned short* __restrict__ WT1b, float* __restrict__ bc1,
                            unsigned short* __restrict__ WT2z, unsigned short* __restrict__ WT2a,
                            unsigned short* __restrict__ WT2b, float* __restrict__ bc2)
{
    int t = blockIdx.x * blockDim.x + threadIdx.x;
    if (t < 16384) {                 // layer 1: [n][k] <- [k][n], n,k < 128
        int n = t >> 7, k = t & 127;
        int in = k * 128 + n;
        WT1z[t] = f2bf(Ws1[in] + Ws1[16384 + in]);
        WT1a[t] = f2bf(Wn1[in]);
        WT1b[t] = f2bf(Wn1[16384 + in]);
    }
    if (t < 8192) {                  // layer 2: n < 64, k < 128
        int n = t >> 7, k = t & 127;
        int in = k * 64 + n;
        WT2z[t] = f2bf(Ws2[in] + Ws2[8192 + in]);
        WT2a[t] = f2bf(Wn2[in]);
        WT2b[t] = f2bf(Wn2[8192 + in]);
    }
    if (t < 128) bc1[t] = b1[t] + b1[128 + t];
    if (t < 64)  bc2[t] = b2[t] + b2[64 + t];
}

// ---- agg L1 (aggregate-first): wave/node, half-wave/edge, 8B lanes ------
// 2 edges per load instruction, 16 edges in flight per unrolled iter.
__global__ __launch_bounds__(256) void
agg1_kernel(const unsigned short* __restrict__ xb,
            const int* __restrict__ csr, const int* __restrict__ off,
            unsigned short* __restrict__ m0, unsigned short* __restrict__ m1,
            int N, int twoE)
{
    int w = blockIdx.x * 4 + (threadIdx.x >> 6);
    int lane = threadIdx.x & 63;
    if (w >= N) return;
    const int half = lane >> 5;
    const int col = (lane & 31) * 4;          // 4 bf16 cols per lane (8B)
    const unsigned short* xc = xb + col;

    float a0 = 0.f, a1 = 0.f, a2 = 0.f, a3 = 0.f;   // rel0
    float b0 = 0.f, b1 = 0.f, b2 = 0.f, b3 = 0.f;   // rel1

    // ---- relation 0 ----
    int o0 = RFL(off[w]);
    int o1 = RFL(off[w + 1]);
    int d0 = o1 - o0;
    int j = o0;
    for (; j + 15 < o1; j += 16) {
        int cc[16];
#pragma unroll
        for (int k = 0; k < 16; ++k) cc[k] = RFL(csr[j + k]);
#pragma unroll
        for (int k = 0; k < 8; ++k) {
            int row = half ? cc[2 * k + 1] : cc[2 * k];
            uint2 v = *(const uint2*)(xc + (size_t)row * 128);
            a0 += bflo(v.x); a1 += bfhi(v.x);
            a2 += bflo(v.y); a3 += bfhi(v.y);
        }
    }
    for (; j + 7 < o1; j += 8) {
        int cc[8];
#pragma unroll
        for (int k = 0; k < 8; ++k) cc[k] = RFL(csr[j + k]);
#pragma unroll
        for (int k = 0; k < 4; ++k) {
            int row = half ? cc[2 * k + 1] : cc[2 * k];
            uint2 v = *(const uint2*)(xc + (size_t)row * 128);
            a0 += bflo(v.x); a1 += bfhi(v.x);
            a2 += bflo(v.y); a3 += bfhi(v.y);
        }
    }
    for (; j + 1 < o1; j += 2) {
        int rlo = RFL(csr[j]);
        int rhi = RFL(csr[j + 1]);
        int row = half ? rhi : rlo;
        uint2 v = *(const uint2*)(xc + (size_t)row * 128);
        a0 += bflo(v.x); a1 += bfhi(v.x);
        a2 += bflo(v.y); a3 += bfhi(v.y);
    }
    if (j < o1) {
        int row = RFL(csr[j]);
        if (half == 0) {
            uint2 v = *(const uint2*)(xc + (size_t)row * 128);
            a0 += bflo(v.x); a1 += bfhi(v.x);
            a2 += bflo(v.y); a3 += bfhi(v.y);
        }
    }

    // ---- relation 1 ----
    int p = N + w;
    o0 = RFL(off[p]);
    o1 = (p + 1 < 2 * N) ? RFL(off[p + 1]) : twoE;
    int d1 = o1 - o0;
    j = o0;
    for (; j + 15 < o1; j += 16) {
        int cc[16];
#pragma unroll
        for (int k = 0; k < 16; ++k) cc[k] = RFL(csr[j + k]);
#pragma unroll
        for (int k = 0; k < 8; ++k) {
            int row = half ? cc[2 * k + 1] : cc[2 * k];
            uint2 v = *(const uint2*)(xc + (size_t)row * 128);
            b0 += bflo(v.x); b1 += bfhi(v.x);
            b2 += bflo(v.y); b3 += bfhi(v.y);
        }
    }
    for (; j + 7 < o1; j += 8) {
        int cc[8];
#pragma unroll
        for (int k = 0; k < 8; ++k) cc[k] = RFL(csr[j + k]);
#pragma unroll
        for (int k = 0; k < 4; ++k) {
            int row = half ? cc[2 * k + 1] : cc[2 * k];
            uint2 v = *(const uint2*)(xc + (size_t)row * 128);
            b0 += bflo(v.x); b1 += bfhi(v.x);
            b2 += bflo(v.y); b3 += bfhi(v.y);
        }
    }
    for (; j + 1 < o1; j += 2) {
        int rlo = RFL(csr[j]);
        int rhi = RFL(csr[j + 1]);
        int row = half ? rhi : rlo;
        uint2 v = *(const uint2*)(xc + (size_t)row * 128);
        b0 += bflo(v.x); b1 += bfhi(v.x);
        b2 += bflo(v.y); b3 += bfhi(v.y);
    }
    if (j < o1) {
        int row = RFL(csr[j]);
        if (half == 0) {
            uint2 v = *(const uint2*)(xc + (size_t)row * 128);
            b0 += bflo(v.x); b1 += bfhi(v.x);
            b2 += bflo(v.y); b3 += bfhi(v.y);
        }
    }

    // cross-half reduce + write
    a0 += __shfl_xor(a0, 32); a1 += __shfl_xor(a1, 32);
    a2 += __shfl_xor(a2, 32); a3 += __shfl_xor(a3, 32);
    b0 += __shfl_xor(b0, 32); b1 += __shfl_xor(b1, 32);
    b2 += __shfl_xor(b2, 32); b3 += __shfl_xor(b3, 32);
    if (half == 0) {
        float inv0 = 1.0f / fmaxf((float)d0, 1.0f);
        float inv1 = 1.0f / fmaxf((float)d1, 1.0f);
        uint2 u0, u1;
        u0.x = pack2(a0 * inv0, a1 * inv0);
        u0.y = pack2(a2 * inv0, a3 * inv0);
        u1.x = pack2(b0 * inv1, b1 * inv1);
        u1.y = pack2(b2 * inv1, b3 * inv1);
        *(uint2*)(m0 + (size_t)w * 128 + col) = u0;
        *(uint2*)(m1 + (size_t)w * 128 + col) = u1;
    }
}

// ---- fused layer-1 GEMM: h1 = relu(x@WTz + m0@WTa + m1@WTb + bias) ------
__global__ __launch_bounds__(256) void
gemm1_fused_kernel(const unsigned short* __restrict__ xb,
                   const unsigned short* __restrict__ m0,
                   const unsigned short* __restrict__ m1,
                   const unsigned short* __restrict__ WTz,
                   const unsigned short* __restrict__ WTa,
                   const unsigned short* __restrict__ WTb,
                   const float* __restrict__ bias,
                   unsigned short* __restrict__ h1b, int N)
{
    __shared__ float eb[64][129];

    const int tid = threadIdx.x;
    const int wave = tid >> 6;
    const int lane = tid & 63;
    const int m = lane & 15;
    const int quad = lane >> 4;

    floatx4 acc[8];
    const floatx4 z4 = {0.f, 0.f, 0.f, 0.f};
#pragma unroll
    for (int t = 0; t < 8; ++t) acc[t] = z4;

    int arow = blockIdx.x * 64 + wave * 16 + m;
    if (arow >= N) arow = N - 1;
    const size_t abase = (size_t)arow * 128 + quad * 8;

#pragma unroll
    for (int s = 0; s < 4; ++s) {
        bf16x8 ax = *(const bf16x8*)(xb + abase + s * 32);
        bf16x8 a0 = *(const bf16x8*)(m0 + abase + s * 32);
        bf16x8 a1 = *(const bf16x8*)(m1 + abase + s * 32);
#pragma unroll
        for (int t = 0; t < 8; ++t) {
            const size_t bo = (size_t)(t * 16 + m) * 128 + s * 32 + quad * 8;
            acc[t] = __builtin_amdgcn_mfma_f32_16x16x32_bf16(
                ax, *(const bf16x8*)(WTz + bo), acc[t], 0, 0, 0);
            acc[t] = __builtin_amdgcn_mfma_f32_16x16x32_bf16(
                a0, *(const bf16x8*)(WTa + bo), acc[t], 0, 0, 0);
            acc[t] = __builtin_amdgcn_mfma_f32_16x16x32_bf16(
                a1, *(const bf16x8*)(WTb + bo), acc[t], 0, 0, 0);
        }
    }

    // C/D: col = lane&15, row = quad*4 + reg -> LDS transpose epilogue
#pragma unroll
    for (int t = 0; t < 8; ++t)
#pragma unroll
        for (int i = 0; i < 4; ++i)
            eb[wave * 16 + quad * 4 + i][t * 16 + m] = acc[t][i];
    __syncthreads();

#pragma unroll
    for (int j = 0; j < 4; ++j) {
        int lr = wave * 16 + j * 4 + quad;
        int grow = blockIdx.x * 64 + lr;
        if (grow < N) {
#pragma unroll
            for (int i = 0; i < 2; ++i) {
                int c0 = (i * 16 + m) * 4;
                float v0 = fmaxf(eb[lr][c0 + 0] + bias[c0 + 0], 0.0f);
                float v1 = fmaxf(eb[lr][c0 + 1] + bias[c0 + 1], 0.0f);
                float v2 = fmaxf(eb[lr][c0 + 2] + bias[c0 + 2], 0.0f);
                float v3 = fmaxf(eb[lr][c0 + 3] + bias[c0 + 3], 0.0f);
                ushort4 u;
                u.x = f2bf(v0); u.y = f2bf(v1); u.z = f2bf(v2); u.w = f2bf(v3);
                *(ushort4*)(h1b + (size_t)grow * 128 + c0) = u;
            }
        }
    }
}

// ---- fused layer-2 GEMM: one pass over h1b -> z2 (f32+bias), t0, t1 -----
__global__ __launch_bounds__(256) void
gemm2_fused_kernel(const unsigned short* __restrict__ Ab,
                   const unsigned short* __restrict__ WTz,
                   const unsigned short* __restrict__ WTa,
                   const unsigned short* __restrict__ WTb,
                   const float* __restrict__ bias,
                   float* __restrict__ zf,
                   unsigned short* __restrict__ ya, unsigned short* __restrict__ yb,
                   int N)
{
    __shared__ float eb[64][65];

    const int tid = threadIdx.x;
    const int wave = tid >> 6;
    const int lane = tid & 63;
    const int m = lane & 15;
    const int quad = lane >> 4;

    floatx4 accz[4], acca[4], accb[4];
    const floatx4 z4 = {0.f, 0.f, 0.f, 0.f};
#pragma unroll
    for (int t = 0; t < 4; ++t) { accz[t] = z4; acca[t] = z4; accb[t] = z4; }

    int arow = blockIdx.x * 64 + wave * 16 + m;
    if (arow >= N) arow = N - 1;
    const unsigned short* aptr = Ab + (size_t)arow * 128 + quad * 8;

#pragma unroll
    for (int s = 0; s < 4; ++s) {
        bf16x8 a = *(const bf16x8*)(aptr + s * 32);
#pragma unroll
        for (int t = 0; t < 4; ++t) {
            const size_t bo = (size_t)(t * 16 + m) * 128 + s * 32 + quad * 8;
            accz[t] = __builtin_amdgcn_mfma_f32_16x16x32_bf16(
                a, *(const bf16x8*)(WTz + bo), accz[t], 0, 0, 0);
            acca[t] = __builtin_amdgcn_mfma_f32_16x16x32_bf16(
                a, *(const bf16x8*)(WTa + bo), acca[t], 0, 0, 0);
            accb[t] = __builtin_amdgcn_mfma_f32_16x16x32_bf16(
                a, *(const bf16x8*)(WTb + bo), accb[t], 0, 0, 0);
        }
    }

    const int grow = blockIdx.x * 64 + wave * 16;

    // ---- round z: f32 + bias ----
#pragma unroll
    for (int t = 0; t < 4; ++t)
#pragma unroll
        for (int i = 0; i < 4; ++i)
            eb[wave * 16 + quad * 4 + i][t * 16 + m] = accz[t][i];
    __syncthreads();
#pragma unroll
    for (int j = 0; j < 4; ++j) {
        int lr = wave * 16 + j * 4 + quad;
        int gr = blockIdx.x * 64 + lr;
        if (gr < N) {
            int c0 = m * 4;
            float4 o;
            o.x = eb[lr][c0 + 0] + bias[c0 + 0];
            o.y = eb[lr][c0 + 1] + bias[c0 + 1];
            o.z = eb[lr][c0 + 2] + bias[c0 + 2];
            o.w = eb[lr][c0 + 3] + bias[c0 + 3];
            *(float4*)(zf + (size_t)gr * 64 + c0) = o;
        }
    }
    __syncthreads();

    // ---- round a: bf16 ----
#pragma unroll
    for (int t = 0; t < 4; ++t)
#pragma unroll
        for (int i = 0; i < 4; ++i)
            eb[wave * 16 + quad * 4 + i][t * 16 + m] = acca[t][i];
    __syncthreads();
#pragma unroll
    for (int j = 0; j < 4; ++j) {
        int lr = wave * 16 + j * 4 + quad;
        int gr = blockIdx.x * 64 + lr;
        if (gr < N) {
            int c0 = m * 4;
            ushort4 u;
            u.x = f2bf(eb[lr][c0 + 0]); u.y = f2bf(eb[lr][c0 + 1]);
            u.z = f2bf(eb[lr][c0 + 2]); u.w = f2bf(eb[lr][c0 + 3]);
            *(ushort4*)(ya + (size_t)gr * 64 + c0) = u;
        }
    }
    __syncthreads();

    // ---- round b: bf16 ----
#pragma unroll
    for (int t = 0; t < 4; ++t)
#pragma unroll
        for (int i = 0; i < 4; ++i)
            eb[wave * 16 + quad * 4 + i][t * 16 + m] = accb[t][i];
    __syncthreads();
#pragma unroll
    for (int j = 0; j < 4; ++j) {
        int lr = wave * 16 + j * 4 + quad;
        int gr = blockIdx.x * 64 + lr;
        if (gr < N) {
            int c0 = m * 4;
            ushort4 u;
            u.x = f2bf(eb[lr][c0 + 0]); u.y = f2bf(eb[lr][c0 + 1]);
            u.z = f2bf(eb[lr][c0 + 2]); u.w = f2bf(eb[lr][c0 + 3]);
            *(ushort4*)(yb + (size_t)gr * 64 + c0) = u;
        }
    }
    (void)grow;
}

// ---- agg L2: wave/node, quarter-wave/edge, 8B lanes, 16 edges/iter ------
__global__ __launch_bounds__(256) void
agg2_kernel(const unsigned short* __restrict__ t0,
            const unsigned short* __restrict__ t1,
            const float* __restrict__ z2,
            const int* __restrict__ csr, const int* __restrict__ off,
            unsigned short* __restrict__ h2b, int N, int twoE)
{
    int w = blockIdx.x * 4 + (threadIdx.x >> 6);
    int lane = threadIdx.x & 63;
    if (w >= N) return;
    const int q = lane >> 4;                 // quarter: which edge of 4
    const int col = (lane & 15) * 4;         // 4 bf16 cols per lane (8B)
    const unsigned short* t0c = t0 + col;
    const unsigned short* t1c = t1 + col;

    float a0 = 0.f, a1 = 0.f, a2 = 0.f, a3 = 0.f;   // rel0
    float b0 = 0.f, b1 = 0.f, b2 = 0.f, b3 = 0.f;   // rel1

    // ---- relation 0 ----
    int o0 = RFL(off[w]);
    int o1 = RFL(off[w + 1]);
    int d0 = o1 - o0;
    int j = o0;
    for (; j + 15 < o1; j += 16) {
        int cc[16];
#pragma unroll
        for (int k = 0; k < 16; ++k) cc[k] = RFL(csr[j + k]);
#pragma unroll
        for (int k = 0; k < 4; ++k) {
            int r01 = (q & 1) ? cc[4 * k + 1] : cc[4 * k];
            int r23 = (q & 1) ? cc[4 * k + 3] : cc[4 * k + 2];
            int row = (q & 2) ? r23 : r01;
            uint2 v = *(const uint2*)(t0c + (size_t)row * 64);
            a0 += bflo(v.x); a1 += bfhi(v.x);
            a2 += bflo(v.y); a3 += bfhi(v.y);
        }
    }
    for (; j + 3 < o1; j += 4) {
        int c0 = RFL(csr[j]), c1 = RFL(csr[j + 1]);
        int c2 = RFL(csr[j + 2]), c3 = RFL(csr[j + 3]);
        int r01 = (q & 1) ? c1 : c0;
        int r23 = (q & 1) ? c3 : c2;
        int row = (q & 2) ? r23 : r01;
        uint2 v = *(const uint2*)(t0c + (size_t)row * 64);
        a0 += bflo(v.x); a1 += bfhi(v.x);
        a2 += bflo(v.y); a3 += bfhi(v.y);
    }
    if (j < o1) {
        int rem = o1 - j;                    // 1..3
        if (q < rem) {
            int row = csr[j + q];
            uint2 v = *(const uint2*)(t0c + (size_t)row * 64);
            a0 += bflo(v.x); a1 += bfhi(v.x);
            a2 += bflo(v.y); a3 += bfhi(v.y);
        }
    }

    // ---- relation 1 ----
    int p = N + w;
    o0 = RFL(off[p]);
    o1 = (p + 1 < 2 * N) ? RFL(off[p + 1]) : twoE;
    int d1 = o1 - o0;
    j = o0;
    for (; j + 15 < o1; j += 16) {
        int cc[16];
#pragma unroll
        for (int k = 0; k < 16; ++k) cc[k] = RFL(csr[j + k]);
#pragma unroll
        for (int k = 0; k < 4; ++k) {
            int r01 = (q & 1) ? cc[4 * k + 1] : cc[4 * k];
            int r23 = (q & 1) ? cc[4 * k + 3] : cc[4 * k + 2];
            int row = (q & 2) ? r23 : r01;
            uint2 v = *(const uint2*)(t1c + (size_t)row * 64);
            b0 += bflo(v.x); b1 += bfhi(v.x);
            b2 += bflo(v.y); b3 += bfhi(v.y);
        }
    }
    for (; j + 3 < o1; j += 4) {
        int c0 = RFL(csr[j]), c1 = RFL(csr[j + 1]);
        int c2 = RFL(csr[j + 2]), c3 = RFL(csr[j + 3]);
        int r01 = (q & 1) ? c1 : c0;
        int r23 = (q & 1) ? c3 : c2;
        int row = (q & 2) ? r23 : r01;
        uint2 v = *(const uint2*)(t1c + (size_t)row * 64);
        b0 += bflo(v.x); b1 += bfhi(v.x);
        b2 += bflo(v.y); b3 += bfhi(v.y);
    }
    if (j < o1) {
        int rem = o1 - j;
        if (q < rem) {
            int row = csr[j + q];
            uint2 v = *(const uint2*)(t1c + (size_t)row * 64);
            b0 += bflo(v.x); b1 += bfhi(v.x);
            b2 += bflo(v.y); b3 += bfhi(v.y);
        }
    }

    // cross-quarter reduce + write
    a0 += __shfl_xor(a0, 16); a1 += __shfl_xor(a1, 16);
    a2 += __shfl_xor(a2, 16); a3 += __shfl_xor(a3, 16);
    b0 += __shfl_xor(b0, 16); b1 += __shfl_xor(b1, 16);
    b2 += __shfl_xor(b2, 16); b3 += __shfl_xor(b3, 16);
    a0 += __shfl_xor(a0, 32); a1 += __shfl_xor(a1, 32);
    a2 += __shfl_xor(a2, 32); a3 += __shfl_xor(a3, 32);
    b0 += __shfl_xor(b0, 32); b1 += __shfl_xor(b1, 32);
    b2 += __shfl_xor(b2, 32); b3 += __shfl_xor(b3, 32);
    if (q == 0) {
        float inv0 = 1.0f / fmaxf((float)d0, 1.0f);
        float inv1 = 1.0f / fmaxf((float)d1, 1.0f);
        float4 z = *(const float4*)(z2 + (size_t)w * 64 + col);
        float h0 = z.x + a0 * inv0 + b0 * inv1;
        float h1 = z.y + a1 * inv0 + b1 * inv1;
        float h2 = z.z + a2 * inv0 + b2 * inv1;
        float h3 = z.w + a3 * inv0 + b3 * inv1;
        uint2 u;
        u.x = pack2(h0, h1);
        u.y = pack2(h2, h3);
        *(uint2*)(h2b + (size_t)w * 64 + col) = u;
    }
}

// ---- score (merged pos+neg): 8 lanes/edge, 128B rows, shfl reduce --------
__global__ __launch_bounds__(256) void
score_kernel(const unsigned short* __restrict__ h, // [N,64] bf16
             const int* __restrict__ edges, const int* __restrict__ neg,
             float* __restrict__ out, int E, int En)
{
    int t = blockIdx.x * blockDim.x + threadIdx.x;
    int e = t >> 3;
    int c = t & 7;
    if (e >= E + En) return;
    int sI, dI, oI;
    if (e < E) { sI = edges[e]; dI = edges[E + e]; oI = e; }
    else { int en = e - E; sI = neg[en]; dI = neg[En + en]; oI = E + en; }
    uint4 va = *(const uint4*)(h + (size_t)sI * 64 + c * 8);
    uint4 vb = *(const uint4*)(h + (size_t)dI * 64 + c * 8);
    float s = 0.0f;
    s = fmaf(bflo(va.x), bflo(vb.x), s);
    s = fmaf(bfhi(va.x), bfhi(vb.x), s);
    s = fmaf(bflo(va.y), bflo(vb.y), s);
    s = fmaf(bfhi(va.y), bfhi(vb.y), s);
    s = fmaf(bflo(va.z), bflo(vb.z), s);
    s = fmaf(bfhi(va.z), bfhi(vb.z), s);
    s = fmaf(bflo(va.w), bflo(vb.w), s);
    s = fmaf(bfhi(va.w), bfhi(vb.w), s);
    s += __shfl_xor(s, 1);
    s += __shfl_xor(s, 2);
    s += __shfl_xor(s, 4);
    if (c == 0) out[oI] = s;
}

extern "C" void kernel_launch(void* const* d_in, const int* in_sizes, int n_in,
                              void* d_out, int out_size, void* d_ws, size_t ws_size,
                              hipStream_t stream)
{
    const float* x     = (const float*)d_in[0];
    const int*   edges = (const int*)d_in[1];
    const int*   neg   = (const int*)d_in[2];
    const float* Wn1   = (const float*)d_in[3];
    const float* Ws1   = (const float*)d_in[4];
    const float* b1    = (const float*)d_in[5];
    const float* Wn2   = (const float*)d_in[6];
    const float* Ws2   = (const float*)d_in[7];
    const float* b2    = (const float*)d_in[8];
    float* out = (float*)d_out;

    const int Fin = 128, R = 2;
    const int N  = in_sizes[0] / Fin;        // 50000
    const int E  = in_sizes[1] / (R * 2);    // 800000
    const int En = in_sizes[2] / 2;          // 800000
    const int twoE = 2 * E;
    const int NBK = (N + BW - 1) / BW;       // 391
    const int rbT = 2 * NBK;

    // ---- workspace layout (aliases noted) ----
    const size_t nb128 = (size_t)N * 128 * sizeof(unsigned short);   // 12.8MB
    char* p = (char*)d_ws;

    uint2* staging = (uint2*)p;                 // [2E] pairs (dead after CSR build)
    float* z2      = (float*)p;                 // [N,64] f32 (layer 2, aliases staging)
    {
        size_t r0 = (size_t)twoE * sizeof(uint2);
        size_t r1 = (size_t)N * 64 * sizeof(float);
        p += (r0 > r1 ? r0 : r1);
    }
    unsigned short* m0  = (unsigned short*)p; p += nb128;  // [N,128] mean rel0 (t0/t1 reuse)
    unsigned short* m1  = (unsigned short*)p; p += nb128;  // [N,128] mean rel1 (h2b reuse)
    unsigned short* xb  = (unsigned short*)p; p += nb128;  // [N,128] bf16 x
    unsigned short* h1b = (unsigned short*)p; p += nb128;  // [N,128] bf16 h1
    unsigned short* WT1z = (unsigned short*)p; p += 16384 * 2;
    unsigned short* WT1a = (unsigned short*)p; p += 16384 * 2;
    unsigned short* WT1b = (unsigned short*)p; p += 16384 * 2;
    unsigned short* WT2z = (unsigned short*)p; p += 8192 * 2;
    unsigned short* WT2a = (unsigned short*)p; p += 8192 * 2;
    unsigned short* WT2b = (unsigned short*)p; p += 8192 * 2;
    float* bc1 = (float*)p; p += 128 * sizeof(float);
    float* bc2 = (float*)p; p += 64 * sizeof(float);
    int* bcnt = (int*)p; p += (size_t)2 * NBK_MAX * sizeof(int);
    int* gcur = (int*)p; p += (size_t)2 * NBK_MAX * sizeof(int);
    int* bko  = (int*)p; p += ((size_t)2 * NBK_MAX + 1) * sizeof(int);
    int* off  = (int*)p; p += (size_t)2 * N * sizeof(int);
    int* csr  = (int*)p;

    unsigned short* t0  = m0;                       // [N,64] bf16
    unsigned short* t1  = m0 + (size_t)N * 64;      // [N,64] bf16
    unsigned short* h2b = m1;                       // [N,64] bf16

    const int BS = 256;
    const int edge_blocks = (twoE + EPB - 1) / EPB;
    const int gx = (N + 63) / 64;

    // ---- CSR build (radix by dst bucket) ----
    hipMemsetAsync(bcnt, 0, (size_t)4 * NBK_MAX * sizeof(int), stream);
    bucket_count_kernel<<<edge_blocks, BS, 0, stream>>>(edges, bcnt, NBK, E);
    bucket_scan_kernel<<<1, 1024, 0, stream>>>(bcnt, bko, rbT, twoE);
    partition_kernel<<<edge_blocks, BS, 0, stream>>>(edges, bko, gcur, staging, NBK, E);
    bucket_csr_kernel<<<rbT, BS, 0, stream>>>(staging, bko, csr, off, NBK, N);

    // ---- prep ----
    cvt_kernel<<<(N * 32 + BS - 1) / BS, BS, 0, stream>>>(x, xb, N * 32);
    prep_kernel<<<(16384 + BS - 1) / BS, BS, 0, stream>>>(
        Ws1, Wn1, b1, Ws2, Wn2, b2,
        WT1z, WT1a, WT1b, bc1, WT2z, WT2a, WT2b, bc2);

    // ---- Layer 1: aggregate raw x, then fused 3-matmul GEMM + bias + relu
    agg1_kernel<<<(N + 3) / 4, BS, 0, stream>>>(xb, csr, off, m0, m1, N, twoE);
    gemm1_fused_kernel<<<gx, BS, 0, stream>>>(xb, m0, m1, WT1z, WT1a, WT1b,
                                              bc1, h1b, N);

    // ---- Layer 2: one fused transform (3 outputs), then aggregate ----
    gemm2_fused_kernel<<<gx, BS, 0, stream>>>(h1b, WT2z, WT2a, WT2b, bc2,
                                              z2, t0, t1, N);
    agg2_kernel<<<(N + 3) / 4, BS, 0, stream>>>(t0, t1, z2, csr, off, h2b, N, twoE);

    // ---- Scores (pos + neg in one launch) ----
    score_kernel<<<((E + En) * 8 + BS - 1) / BS, BS, 0, stream>>>(
        h2b, edges, neg, out, E, En);
}

// Round 3
// 382.777 us; speedup vs baseline: 1.1508x; 1.1508x over previous
//
#include <hip/hip_runtime.h>

// ---------------------------------------------------------------------------
// GraphSAGE 2-layer hetero (R=2) + edge dot scorer.  Round 11:
//  * agg1: REVERTED to round-9 full-wave structure (4B/lane, named scalars,
//    RFL csr indices). Round-10's cc[16] arrays + shfl caused compiler
//    array materialization: LDS 16KB + 9M bank conflicts + 200MB spill
//    writes -> 2x regression. Main loop deepened 8->16 with NAMED scalars
//    only (16 gathers in flight, avg degree is 16).
//  * agg2: reverted to round-9 version verbatim (half-wave, stride-2).
//  * kept from round 10: gemm2_fused (h1b read once, 3 outputs in one
//    kernel) and merged pos+neg score launch.
//  * Layer 1 stays aggregate-first + fused 3-matmul GEMM.
//  * CSR build (BW=128 buckets) unchanged.
// ---------------------------------------------------------------------------

#define BW 128            // nodes per radix bucket (pow2)
#define NBK_MAX 1024
#define EPB 8192          // edges per block in radix passes

typedef __attribute__((ext_vector_type(8))) short bf16x8;
typedef __attribute__((ext_vector_type(4))) float floatx4;

__device__ __forceinline__ unsigned short f2bf(float f) {
    unsigned u = __float_as_uint(f);
    unsigned r = u + 0x7FFFu + ((u >> 16) & 1u);
    return (unsigned short)(r >> 16);
}
__device__ __forceinline__ unsigned pack2(float a, float b) {
    return (unsigned)f2bf(a) | ((unsigned)f2bf(b) << 16);
}
__device__ __forceinline__ float bflo(unsigned v) { return __uint_as_float(v << 16); }
__device__ __forceinline__ float bfhi(unsigned v) { return __uint_as_float(v & 0xFFFF0000u); }
#define RFL(x) __builtin_amdgcn_readfirstlane(x)

// ---- radix pass A: per-(r,bucket) counts --------------------------------
__global__ __launch_bounds__(256) void
bucket_count_kernel(const int* __restrict__ edges, int* __restrict__ bcnt,
                    int NBK, int E)
{
    __shared__ int cnt[2 * NBK_MAX];
    const int rbT = 2 * NBK;
    const int t = threadIdx.x;
    for (int k = t; k < rbT; k += 256) cnt[k] = 0;
    __syncthreads();
    long long start = (long long)blockIdx.x * EPB;
    long long twoE = 2LL * E;
    for (int u = 0; u < EPB / 256; ++u) {
        long long idx = start + u * 256 + t;
        if (idx < twoE) {
            int r = idx >= E;
            int e = (int)(idx - (long long)r * E);
            int d = edges[(size_t)r * 2 * E + E + e];
            atomicAdd(&cnt[r * NBK + (d >> 7)], 1);
        }
    }
    __syncthreads();
    for (int k = t; k < rbT; k += 256)
        if (cnt[k]) atomicAdd(&bcnt[k], cnt[k]);
}

// ---- radix pass B: exclusive scan of bucket counts ----------------------
__global__ __launch_bounds__(1024) void
bucket_scan_kernel(const int* __restrict__ bcnt, int* __restrict__ bko,
                   int rbT, int twoE)
{
    __shared__ int sm[1024];
    int t = threadIdx.x;
    int v = (t < rbT) ? bcnt[t] : 0;
    sm[t] = v;
    __syncthreads();
    for (int s = 1; s < 1024; s <<= 1) {
        int u = (t >= s) ? sm[t - s] : 0;
        __syncthreads();
        sm[t] += u;
        __syncthreads();
    }
    if (t < rbT) bko[t] = sm[t] - v;
    if (t == 0) bko[rbT] = twoE;
}

// ---- radix pass C: partition into bucket-grouped (src,dst) pairs --------
__global__ __launch_bounds__(256) void
partition_kernel(const int* __restrict__ edges, const int* __restrict__ bko,
                 int* __restrict__ gcur, uint2* __restrict__ staging,
                 int NBK, int E)
{
    __shared__ int cnt[2 * NBK_MAX];
    __shared__ int base[2 * NBK_MAX];
    const int rbT = 2 * NBK;
    const int t = threadIdx.x;
    for (int k = t; k < rbT; k += 256) cnt[k] = 0;
    __syncthreads();
    long long start = (long long)blockIdx.x * EPB;
    long long twoE = 2LL * E;
    for (int u = 0; u < EPB / 256; ++u) {
        long long idx = start + u * 256 + t;
        if (idx < twoE) {
            int r = idx >= E;
            int e = (int)(idx - (long long)r * E);
            int d = edges[(size_t)r * 2 * E + E + e];
            atomicAdd(&cnt[r * NBK + (d >> 7)], 1);
        }
    }
    __syncthreads();
    for (int k = t; k < rbT; k += 256) {
        int c0 = cnt[k];
        if (c0) base[k] = bko[k] + atomicAdd(&gcur[k], c0);
        cnt[k] = 0;
    }
    __syncthreads();
    for (int u = 0; u < EPB / 256; ++u) {
        long long idx = start + u * 256 + t;
        if (idx < twoE) {
            int r = idx >= E;
            int e = (int)(idx - (long long)r * E);
            int s = edges[(size_t)r * 2 * E + e];
            int d = edges[(size_t)r * 2 * E + E + e];
            int rb = r * NBK + (d >> 7);
            int pos = atomicAdd(&cnt[rb], 1);
            staging[(size_t)base[rb] + pos] = make_uint2((unsigned)s, (unsigned)d);
        }
    }
}

// ---- radix pass D: per-bucket node hist/scan -> off[] and csr[] ----------
__global__ __launch_bounds__(256) void
bucket_csr_kernel(const uint2* __restrict__ staging, const int* __restrict__ bko,
                  int* __restrict__ csr, int* __restrict__ off,
                  int NBK, int N)
{
    __shared__ int hist[BW], excl[BW], cur[BW], sc[BW];
    const int rb = blockIdx.x;
    const int r = rb / NBK;
    const int b = rb % NBK;
    const int node0 = b * BW;
    const int nn = min(BW, N - node0);
    const int cbase = bko[rb];
    const int c = bko[rb + 1] - cbase;
    const int t = threadIdx.x;

    if (t < BW) { hist[t] = 0; cur[t] = 0; }
    __syncthreads();
    for (int k = t; k < c; k += 256)
        atomicAdd(&hist[(int)staging[(size_t)cbase + k].y - node0], 1);
    __syncthreads();
    if (t < BW) sc[t] = hist[t];
    __syncthreads();
    for (int s = 1; s < BW; s <<= 1) {
        int v = (t < BW && t >= s) ? sc[t - s] : 0;
        __syncthreads();
        if (t < BW) sc[t] += v;
        __syncthreads();
    }
    if (t < BW) excl[t] = sc[t] - hist[t];
    if (t < nn) off[(size_t)r * N + node0 + t] = cbase + excl[t];
    __syncthreads();
    for (int k = t; k < c; k += 256) {
        uint2 pr = staging[(size_t)cbase + k];
        int l = (int)pr.y - node0;
        int pos = atomicAdd(&cur[l], 1);
        csr[(size_t)cbase + excl[l] + pos] = (int)pr.x;
    }
}

// ---- f32 -> bf16 --------------------------------------------------------
__global__ void cvt_kernel(const float* __restrict__ in,
                           unsigned short* __restrict__ o, int n4)
{
    int t = blockIdx.x * blockDim.x + threadIdx.x;
    if (t >= n4) return;
    float4 v = ((const float4*)in)[t];
    ushort4 r;
    r.x = f2bf(v.x); r.y = f2bf(v.y); r.z = f2bf(v.z); r.w = f2bf(v.w);
    ((ushort4*)o)[t] = r;
}

// ---- weight prep: combined-Wself / Wn -> bf16 W^T rows, biases ----------
__global__ void prep_kernel(const float* __restrict__ Ws1, const float* __restrict__ Wn1,
                            const float* __restrict__ b1,
                            const float* __restrict__ Ws2, const float* __restrict__ Wn2,
                            const float* __restrict__ b2,
                            unsigned short* __restrict__ WT1z, unsigned short* __restrict__ WT1a,
                            unsigned short* __restrict__ WT1b, float* __restrict__ bc1,
                            unsigned short* __restrict__ WT2z, unsigned short* __restrict__ WT2a,
                            unsigned short* __restrict__ WT2b, float* __restrict__ bc2)
{
    int t = blockIdx.x * blockDim.x + threadIdx.x;
    if (t < 16384) {                 // layer 1: [n][k] <- [k][n], n,k < 128
        int n = t >> 7, k = t & 127;
        int in = k * 128 + n;
        WT1z[t] = f2bf(Ws1[in] + Ws1[16384 + in]);
        WT1a[t] = f2bf(Wn1[in]);
        WT1b[t] = f2bf(Wn1[16384 + in]);
    }
    if (t < 8192) {                  // layer 2: n < 64, k < 128
        int n = t >> 7, k = t & 127;
        int in = k * 64 + n;
        WT2z[t] = f2bf(Ws2[in] + Ws2[8192 + in]);
        WT2a[t] = f2bf(Wn2[in]);
        WT2b[t] = f2bf(Wn2[8192 + in]);
    }
    if (t < 128) bc1[t] = b1[t] + b1[128 + t];
    if (t < 64)  bc2[t] = b2[t] + b2[64 + t];
}

// ---- agg L1 (aggregate-first): wave per node, 4B/lane, unroll x16 -------
// Named scalars ONLY (no arrays -> no compiler array materialization).
__global__ __launch_bounds__(256) void
agg1_kernel(const unsigned short* __restrict__ xb,
            const int* __restrict__ csr, const int* __restrict__ off,
            unsigned short* __restrict__ m0, unsigned short* __restrict__ m1,
            int N, int twoE)
{
    int w = blockIdx.x * 4 + (threadIdx.x >> 6);
    int lane = threadIdx.x & 63;
    if (w >= N) return;
    const int col = lane * 2;
    const unsigned short* xc = xb + col;

    float sx0 = 0.f, sy0 = 0.f, sx1 = 0.f, sy1 = 0.f;

    // ---- relation 0 ----
    int o0 = RFL(off[w]);
    int o1 = RFL(off[w + 1]);
    int d0 = o1 - o0;
    int j = o0;
    for (; j + 15 < o1; j += 16) {
        int s0 = RFL(csr[j]);      int s1 = RFL(csr[j + 1]);
        int s2 = RFL(csr[j + 2]);  int s3 = RFL(csr[j + 3]);
        int s4 = RFL(csr[j + 4]);  int s5 = RFL(csr[j + 5]);
        int s6 = RFL(csr[j + 6]);  int s7 = RFL(csr[j + 7]);
        int s8 = RFL(csr[j + 8]);  int s9 = RFL(csr[j + 9]);
        int sa = RFL(csr[j + 10]); int sb = RFL(csr[j + 11]);
        int sc = RFL(csr[j + 12]); int sd = RFL(csr[j + 13]);
        int se = RFL(csr[j + 14]); int sf = RFL(csr[j + 15]);
        unsigned a0 = *(const unsigned*)(xc + (size_t)s0 * 128);
        unsigned a1 = *(const unsigned*)(xc + (size_t)s1 * 128);
        unsigned a2 = *(const unsigned*)(xc + (size_t)s2 * 128);
        unsigned a3 = *(const unsigned*)(xc + (size_t)s3 * 128);
        unsigned a4 = *(const unsigned*)(xc + (size_t)s4 * 128);
        unsigned a5 = *(const unsigned*)(xc + (size_t)s5 * 128);
        unsigned a6 = *(const unsigned*)(xc + (size_t)s6 * 128);
        unsigned a7 = *(const unsigned*)(xc + (size_t)s7 * 128);
        unsigned a8 = *(const unsigned*)(xc + (size_t)s8 * 128);
        unsigned a9 = *(const unsigned*)(xc + (size_t)s9 * 128);
        unsigned aa = *(const unsigned*)(xc + (size_t)sa * 128);
        unsigned ab = *(const unsigned*)(xc + (size_t)sb * 128);
        unsigned ac = *(const unsigned*)(xc + (size_t)sc * 128);
        unsigned ad = *(const unsigned*)(xc + (size_t)sd * 128);
        unsigned ae = *(const unsigned*)(xc + (size_t)se * 128);
        unsigned af = *(const unsigned*)(xc + (size_t)sf * 128);
        sx0 += (((bflo(a0) + bflo(a1)) + (bflo(a2) + bflo(a3))) +
                ((bflo(a4) + bflo(a5)) + (bflo(a6) + bflo(a7)))) +
               (((bflo(a8) + bflo(a9)) + (bflo(aa) + bflo(ab))) +
                ((bflo(ac) + bflo(ad)) + (bflo(ae) + bflo(af))));
        sy0 += (((bfhi(a0) + bfhi(a1)) + (bfhi(a2) + bfhi(a3))) +
                ((bfhi(a4) + bfhi(a5)) + (bfhi(a6) + bfhi(a7)))) +
               (((bfhi(a8) + bfhi(a9)) + (bfhi(aa) + bfhi(ab))) +
                ((bfhi(ac) + bfhi(ad)) + (bfhi(ae) + bfhi(af))));
    }
    for (; j + 7 < o1; j += 8) {
        int s0 = RFL(csr[j]);     int s1 = RFL(csr[j + 1]);
        int s2 = RFL(csr[j + 2]); int s3 = RFL(csr[j + 3]);
        int s4 = RFL(csr[j + 4]); int s5 = RFL(csr[j + 5]);
        int s6 = RFL(csr[j + 6]); int s7 = RFL(csr[j + 7]);
        unsigned a0 = *(const unsigned*)(xc + (size_t)s0 * 128);
        unsigned a1 = *(const unsigned*)(xc + (size_t)s1 * 128);
        unsigned a2 = *(const unsigned*)(xc + (size_t)s2 * 128);
        unsigned a3 = *(const unsigned*)(xc + (size_t)s3 * 128);
        unsigned a4 = *(const unsigned*)(xc + (size_t)s4 * 128);
        unsigned a5 = *(const unsigned*)(xc + (size_t)s5 * 128);
        unsigned a6 = *(const unsigned*)(xc + (size_t)s6 * 128);
        unsigned a7 = *(const unsigned*)(xc + (size_t)s7 * 128);
        sx0 += ((bflo(a0) + bflo(a1)) + (bflo(a2) + bflo(a3))) +
               ((bflo(a4) + bflo(a5)) + (bflo(a6) + bflo(a7)));
        sy0 += ((bfhi(a0) + bfhi(a1)) + (bfhi(a2) + bfhi(a3))) +
               ((bfhi(a4) + bfhi(a5)) + (bfhi(a6) + bfhi(a7)));
    }
    for (; j < o1; ++j) {
        int s0 = RFL(csr[j]);
        unsigned a = *(const unsigned*)(xc + (size_t)s0 * 128);
        sx0 += bflo(a); sy0 += bfhi(a);
    }

    // ---- relation 1 ----
    int p = N + w;
    o0 = RFL(off[p]);
    o1 = (p + 1 < 2 * N) ? RFL(off[p + 1]) : twoE;
    int d1 = o1 - o0;
    j = o0;
    for (; j + 15 < o1; j += 16) {
        int s0 = RFL(csr[j]);      int s1 = RFL(csr[j + 1]);
        int s2 = RFL(csr[j + 2]);  int s3 = RFL(csr[j + 3]);
        int s4 = RFL(csr[j + 4]);  int s5 = RFL(csr[j + 5]);
        int s6 = RFL(csr[j + 6]);  int s7 = RFL(csr[j + 7]);
        int s8 = RFL(csr[j + 8]);  int s9 = RFL(csr[j + 9]);
        int sa = RFL(csr[j + 10]); int sb = RFL(csr[j + 11]);
        int sc = RFL(csr[j + 12]); int sd = RFL(csr[j + 13]);
        int se = RFL(csr[j + 14]); int sf = RFL(csr[j + 15]);
        unsigned a0 = *(const unsigned*)(xc + (size_t)s0 * 128);
        unsigned a1 = *(const unsigned*)(xc + (size_t)s1 * 128);
        unsigned a2 = *(const unsigned*)(xc + (size_t)s2 * 128);
        unsigned a3 = *(const unsigned*)(xc + (size_t)s3 * 128);
        unsigned a4 = *(const unsigned*)(xc + (size_t)s4 * 128);
        unsigned a5 = *(const unsigned*)(xc + (size_t)s5 * 128);
        unsigned a6 = *(const unsigned*)(xc + (size_t)s6 * 128);
        unsigned a7 = *(const unsigned*)(xc + (size_t)s7 * 128);
        unsigned a8 = *(const unsigned*)(xc + (size_t)s8 * 128);
        unsigned a9 = *(const unsigned*)(xc + (size_t)s9 * 128);
        unsigned aa = *(const unsigned*)(xc + (size_t)sa * 128);
        unsigned ab = *(const unsigned*)(xc + (size_t)sb * 128);
        unsigned ac = *(const unsigned*)(xc + (size_t)sc * 128);
        unsigned ad = *(const unsigned*)(xc + (size_t)sd * 128);
        unsigned ae = *(const unsigned*)(xc + (size_t)se * 128);
        unsigned af = *(const unsigned*)(xc + (size_t)sf * 128);
        sx1 += (((bflo(a0) + bflo(a1)) + (bflo(a2) + bflo(a3))) +
                ((bflo(a4) + bflo(a5)) + (bflo(a6) + bflo(a7)))) +
               (((bflo(a8) + bflo(a9)) + (bflo(aa) + bflo(ab))) +
                ((bflo(ac) + bflo(ad)) + (bflo(ae) + bflo(af))));
        sy1 += (((bfhi(a0) + bfhi(a1)) + (bfhi(a2) + bfhi(a3))) +
                ((bfhi(a4) + bfhi(a5)) + (bfhi(a6) + bfhi(a7)))) +
               (((bfhi(a8) + bfhi(a9)) + (bfhi(aa) + bfhi(ab))) +
                ((bfhi(ac) + bfhi(ad)) + (bfhi(ae) + bfhi(af))));
    }
    for (; j + 7 < o1; j += 8) {
        int s0 = RFL(csr[j]);     int s1 = RFL(csr[j + 1]);
        int s2 = RFL(csr[j + 2]); int s3 = RFL(csr[j + 3]);
        int s4 = RFL(csr[j + 4]); int s5 = RFL(csr[j + 5]);
        int s6 = RFL(csr[j + 6]); int s7 = RFL(csr[j + 7]);
        unsigned a0 = *(const unsigned*)(xc + (size_t)s0 * 128);
        unsigned a1 = *(const unsigned*)(xc + (size_t)s1 * 128);
        unsigned a2 = *(const unsigned*)(xc + (size_t)s2 * 128);
        unsigned a3 = *(const unsigned*)(xc + (size_t)s3 * 128);
        unsigned a4 = *(const unsigned*)(xc + (size_t)s4 * 128);
        unsigned a5 = *(const unsigned*)(xc + (size_t)s5 * 128);
        unsigned a6 = *(const unsigned*)(xc + (size_t)s6 * 128);
        unsigned a7 = *(const unsigned*)(xc + (size_t)s7 * 128);
        sx1 += ((bflo(a0) + bflo(a1)) + (bflo(a2) + bflo(a3))) +
               ((bflo(a4) + bflo(a5)) + (bflo(a6) + bflo(a7)));
        sy1 += ((bfhi(a0) + bfhi(a1)) + (bfhi(a2) + bfhi(a3))) +
               ((bfhi(a4) + bfhi(a5)) + (bfhi(a6) + bfhi(a7)));
    }
    for (; j < o1; ++j) {
        int s0 = RFL(csr[j]);
        unsigned a = *(const unsigned*)(xc + (size_t)s0 * 128);
        sx1 += bflo(a); sy1 += bfhi(a);
    }

    float inv0 = 1.0f / fmaxf((float)d0, 1.0f);
    float inv1 = 1.0f / fmaxf((float)d1, 1.0f);
    *(unsigned*)(m0 + (size_t)w * 128 + col) = pack2(sx0 * inv0, sy0 * inv0);
    *(unsigned*)(m1 + (size_t)w * 128 + col) = pack2(sx1 * inv1, sy1 * inv1);
}

// ---- fused layer-1 GEMM: h1 = relu(x@WTz + m0@WTa + m1@WTb + bias) ------
__global__ __launch_bounds__(256) void
gemm1_fused_kernel(const unsigned short* __restrict__ xb,
                   const unsigned short* __restrict__ m0,
                   const unsigned short* __restrict__ m1,
                   const unsigned short* __restrict__ WTz,
                   const unsigned short* __restrict__ WTa,
                   const unsigned short* __restrict__ WTb,
                   const float* __restrict__ bias,
                   unsigned short* __restrict__ h1b, int N)
{
    __shared__ float eb[64][129];

    const int tid = threadIdx.x;
    const int wave = tid >> 6;
    const int lane = tid & 63;
    const int m = lane & 15;
    const int quad = lane >> 4;

    floatx4 acc[8];
    const floatx4 z4 = {0.f, 0.f, 0.f, 0.f};
#pragma unroll
    for (int t = 0; t < 8; ++t) acc[t] = z4;

    int arow = blockIdx.x * 64 + wave * 16 + m;
    if (arow >= N) arow = N - 1;
    const size_t abase = (size_t)arow * 128 + quad * 8;

#pragma unroll
    for (int s = 0; s < 4; ++s) {
        bf16x8 ax = *(const bf16x8*)(xb + abase + s * 32);
        bf16x8 a0 = *(const bf16x8*)(m0 + abase + s * 32);
        bf16x8 a1 = *(const bf16x8*)(m1 + abase + s * 32);
#pragma unroll
        for (int t = 0; t < 8; ++t) {
            const size_t bo = (size_t)(t * 16 + m) * 128 + s * 32 + quad * 8;
            acc[t] = __builtin_amdgcn_mfma_f32_16x16x32_bf16(
                ax, *(const bf16x8*)(WTz + bo), acc[t], 0, 0, 0);
            acc[t] = __builtin_amdgcn_mfma_f32_16x16x32_bf16(
                a0, *(const bf16x8*)(WTa + bo), acc[t], 0, 0, 0);
            acc[t] = __builtin_amdgcn_mfma_f32_16x16x32_bf16(
                a1, *(const bf16x8*)(WTb + bo), acc[t], 0, 0, 0);
        }
    }

    // C/D: col = lane&15, row = quad*4 + reg -> LDS transpose epilogue
#pragma unroll
    for (int t = 0; t < 8; ++t)
#pragma unroll
        for (int i = 0; i < 4; ++i)
            eb[wave * 16 + quad * 4 + i][t * 16 + m] = acc[t][i];
    __syncthreads();

#pragma unroll
    for (int j = 0; j < 4; ++j) {
        int lr = wave * 16 + j * 4 + quad;
        int grow = blockIdx.x * 64 + lr;
        if (grow < N) {
#pragma unroll
            for (int i = 0; i < 2; ++i) {
                int c0 = (i * 16 + m) * 4;
                float v0 = fmaxf(eb[lr][c0 + 0] + bias[c0 + 0], 0.0f);
                float v1 = fmaxf(eb[lr][c0 + 1] + bias[c0 + 1], 0.0f);
                float v2 = fmaxf(eb[lr][c0 + 2] + bias[c0 + 2], 0.0f);
                float v3 = fmaxf(eb[lr][c0 + 3] + bias[c0 + 3], 0.0f);
                ushort4 u;
                u.x = f2bf(v0); u.y = f2bf(v1); u.z = f2bf(v2); u.w = f2bf(v3);
                *(ushort4*)(h1b + (size_t)grow * 128 + c0) = u;
            }
        }
    }
}

// ---- fused layer-2 GEMM: one pass over h1b -> z2 (f32+bias), t0, t1 -----
__global__ __launch_bounds__(256) void
gemm2_fused_kernel(const unsigned short* __restrict__ Ab,
                   const unsigned short* __restrict__ WTz,
                   const unsigned short* __restrict__ WTa,
                   const unsigned short* __restrict__ WTb,
                   const float* __restrict__ bias,
                   float* __restrict__ zf,
                   unsigned short* __restrict__ ya, unsigned short* __restrict__ yb,
                   int N)
{
    __shared__ float eb[64][65];

    const int tid = threadIdx.x;
    const int wave = tid >> 6;
    const int lane = tid & 63;
    const int m = lane & 15;
    const int quad = lane >> 4;

    floatx4 accz[4], acca[4], accb[4];
    const floatx4 z4 = {0.f, 0.f, 0.f, 0.f};
#pragma unroll
    for (int t = 0; t < 4; ++t) { accz[t] = z4; acca[t] = z4; accb[t] = z4; }

    int arow = blockIdx.x * 64 + wave * 16 + m;
    if (arow >= N) arow = N - 1;
    const unsigned short* aptr = Ab + (size_t)arow * 128 + quad * 8;

#pragma unroll
    for (int s = 0; s < 4; ++s) {
        bf16x8 a = *(const bf16x8*)(aptr + s * 32);
#pragma unroll
        for (int t = 0; t < 4; ++t) {
            const size_t bo = (size_t)(t * 16 + m) * 128 + s * 32 + quad * 8;
            accz[t] = __builtin_amdgcn_mfma_f32_16x16x32_bf16(
                a, *(const bf16x8*)(WTz + bo), accz[t], 0, 0, 0);
            acca[t] = __builtin_amdgcn_mfma_f32_16x16x32_bf16(
                a, *(const bf16x8*)(WTa + bo), acca[t], 0, 0, 0);
            accb[t] = __builtin_amdgcn_mfma_f32_16x16x32_bf16(
                a, *(const bf16x8*)(WTb + bo), accb[t], 0, 0, 0);
        }
    }

    // ---- round z: f32 + bias ----
#pragma unroll
    for (int t = 0; t < 4; ++t)
#pragma unroll
        for (int i = 0; i < 4; ++i)
            eb[wave * 16 + quad * 4 + i][t * 16 + m] = accz[t][i];
    __syncthreads();
#pragma unroll
    for (int j = 0; j < 4; ++j) {
        int lr = wave * 16 + j * 4 + quad;
        int gr = blockIdx.x * 64 + lr;
        if (gr < N) {
            int c0 = m * 4;
            float4 o;
            o.x = eb[lr][c0 + 0] + bias[c0 + 0];
            o.y = eb[lr][c0 + 1] + bias[c0 + 1];
            o.z = eb[lr][c0 + 2] + bias[c0 + 2];
            o.w = eb[lr][c0 + 3] + bias[c0 + 3];
            *(float4*)(zf + (size_t)gr * 64 + c0) = o;
        }
    }
    __syncthreads();

    // ---- round a: bf16 ----
#pragma unroll
    for (int t = 0; t < 4; ++t)
#pragma unroll
        for (int i = 0; i < 4; ++i)
            eb[wave * 16 + quad * 4 + i][t * 16 + m] = acca[t][i];
    __syncthreads();
#pragma unroll
    for (int j = 0; j < 4; ++j) {
        int lr = wave * 16 + j * 4 + quad;
        int gr = blockIdx.x * 64 + lr;
        if (gr < N) {
            int c0 = m * 4;
            ushort4 u;
            u.x = f2bf(eb[lr][c0 + 0]); u.y = f2bf(eb[lr][c0 + 1]);
            u.z = f2bf(eb[lr][c0 + 2]); u.w = f2bf(eb[lr][c0 + 3]);
            *(ushort4*)(ya + (size_t)gr * 64 + c0) = u;
        }
    }
    __syncthreads();

    // ---- round b: bf16 ----
#pragma unroll
    for (int t = 0; t < 4; ++t)
#pragma unroll
        for (int i = 0; i < 4; ++i)
            eb[wave * 16 + quad * 4 + i][t * 16 + m] = accb[t][i];
    __syncthreads();
#pragma unroll
    for (int j = 0; j < 4; ++j) {
        int lr = wave * 16 + j * 4 + quad;
        int gr = blockIdx.x * 64 + lr;
        if (gr < N) {
            int c0 = m * 4;
            ushort4 u;
            u.x = f2bf(eb[lr][c0 + 0]); u.y = f2bf(eb[lr][c0 + 1]);
            u.z = f2bf(eb[lr][c0 + 2]); u.w = f2bf(eb[lr][c0 + 3]);
            *(ushort4*)(yb + (size_t)gr * 64 + c0) = u;
        }
    }
}

// ---- agg L2: wave per node, 64 cols, 2 edges/iter, unroll x4 (round 9) --
__global__ __launch_bounds__(256) void
agg2_kernel(const unsigned short* __restrict__ t0,
            const unsigned short* __restrict__ t1,
            const float* __restrict__ z2,
            const int* __restrict__ csr, const int* __restrict__ off,
            unsigned short* __restrict__ h2b, int N, int twoE)
{
    int w = blockIdx.x * 4 + (threadIdx.x >> 6);
    int lane = threadIdx.x & 63;
    if (w >= N) return;
    const int half = lane >> 5;
    const int col = (lane & 31) * 2;

    float sx0 = 0.f, sy0 = 0.f, sx1 = 0.f, sy1 = 0.f;
    int o0 = RFL(off[w]);
    int o1 = RFL(off[w + 1]);
    int d0 = o1 - o0;
    int j = o0 + half;
    for (; j + 6 < o1; j += 8) {
        int s0 = csr[j], s1 = csr[j + 2], s2 = csr[j + 4], s3 = csr[j + 6];
        unsigned a0 = *(const unsigned*)(t0 + (size_t)s0 * 64 + col);
        unsigned a1 = *(const unsigned*)(t0 + (size_t)s1 * 64 + col);
        unsigned a2 = *(const unsigned*)(t0 + (size_t)s2 * 64 + col);
        unsigned a3 = *(const unsigned*)(t0 + (size_t)s3 * 64 + col);
        sx0 += (bflo(a0) + bflo(a1)) + (bflo(a2) + bflo(a3));
        sy0 += (bfhi(a0) + bfhi(a1)) + (bfhi(a2) + bfhi(a3));
    }
    for (; j < o1; j += 2) {
        unsigned a = *(const unsigned*)(t0 + (size_t)csr[j] * 64 + col);
        sx0 += bflo(a); sy0 += bfhi(a);
    }
    int p = N + w;
    o0 = RFL(off[p]);
    o1 = (p + 1 < 2 * N) ? RFL(off[p + 1]) : twoE;
    int d1 = o1 - o0;
    j = o0 + half;
    for (; j + 6 < o1; j += 8) {
        int s0 = csr[j], s1 = csr[j + 2], s2 = csr[j + 4], s3 = csr[j + 6];
        unsigned a0 = *(const unsigned*)(t1 + (size_t)s0 * 64 + col);
        unsigned a1 = *(const unsigned*)(t1 + (size_t)s1 * 64 + col);
        unsigned a2 = *(const unsigned*)(t1 + (size_t)s2 * 64 + col);
        unsigned a3 = *(const unsigned*)(t1 + (size_t)s3 * 64 + col);
        sx1 += (bflo(a0) + bflo(a1)) + (bflo(a2) + bflo(a3));
        sy1 += (bfhi(a0) + bfhi(a1)) + (bfhi(a2) + bfhi(a3));
    }
    for (; j < o1; j += 2) {
        unsigned a = *(const unsigned*)(t1 + (size_t)csr[j] * 64 + col);
        sx1 += bflo(a); sy1 += bfhi(a);
    }
    sx0 += __shfl_xor(sx0, 32);
    sy0 += __shfl_xor(sy0, 32);
    sx1 += __shfl_xor(sx1, 32);
    sy1 += __shfl_xor(sy1, 32);
    if (half == 0) {
        float inv0 = 1.0f / fmaxf((float)d0, 1.0f);
        float inv1 = 1.0f / fmaxf((float)d1, 1.0f);
        float2 z = *(const float2*)(z2 + (size_t)w * 64 + col);
        float hx = z.x + sx0 * inv0 + sx1 * inv1;
        float hy = z.y + sy0 * inv0 + sy1 * inv1;
        *(unsigned*)(h2b + (size_t)w * 64 + col) = pack2(hx, hy);
    }
}

// ---- score (merged pos+neg): 8 lanes/edge, 128B rows, shfl reduce --------
__global__ __launch_bounds__(256) void
score_kernel(const unsigned short* __restrict__ h, // [N,64] bf16
             const int* __restrict__ edges, const int* __restrict__ neg,
             float* __restrict__ out, int E, int En)
{
    int t = blockIdx.x * blockDim.x + threadIdx.x;
    int e = t >> 3;
    int c = t & 7;
    if (e >= E + En) return;
    int sI, dI, oI;
    if (e < E) { sI = edges[e]; dI = edges[E + e]; oI = e; }
    else { int en = e - E; sI = neg[en]; dI = neg[En + en]; oI = E + en; }
    uint4 va = *(const uint4*)(h + (size_t)sI * 64 + c * 8);
    uint4 vb = *(const uint4*)(h + (size_t)dI * 64 + c * 8);
    float s = 0.0f;
    s = fmaf(bflo(va.x), bflo(vb.x), s);
    s = fmaf(bfhi(va.x), bfhi(vb.x), s);
    s = fmaf(bflo(va.y), bflo(vb.y), s);
    s = fmaf(bfhi(va.y), bfhi(vb.y), s);
    s = fmaf(bflo(va.z), bflo(vb.z), s);
    s = fmaf(bfhi(va.z), bfhi(vb.z), s);
    s = fmaf(bflo(va.w), bflo(vb.w), s);
    s = fmaf(bfhi(va.w), bfhi(vb.w), s);
    s += __shfl_xor(s, 1);
    s += __shfl_xor(s, 2);
    s += __shfl_xor(s, 4);
    if (c == 0) out[oI] = s;
}

extern "C" void kernel_launch(void* const* d_in, const int* in_sizes, int n_in,
                              void* d_out, int out_size, void* d_ws, size_t ws_size,
                              hipStream_t stream)
{
    const float* x     = (const float*)d_in[0];
    const int*   edges = (const int*)d_in[1];
    const int*   neg   = (const int*)d_in[2];
    const float* Wn1   = (const float*)d_in[3];
    const float* Ws1   = (const float*)d_in[4];
    const float* b1    = (const float*)d_in[5];
    const float* Wn2   = (const float*)d_in[6];
    const float* Ws2   = (const float*)d_in[7];
    const float* b2    = (const float*)d_in[8];
    float* out = (float*)d_out;

    const int Fin = 128, R = 2;
    const int N  = in_sizes[0] / Fin;        // 50000
    const int E  = in_sizes[1] / (R * 2);    // 800000
    const int En = in_sizes[2] / 2;          // 800000
    const int twoE = 2 * E;
    const int NBK = (N + BW - 1) / BW;       // 391
    const int rbT = 2 * NBK;

    // ---- workspace layout (aliases noted) ----
    const size_t nb128 = (size_t)N * 128 * sizeof(unsigned short);   // 12.8MB
    char* p = (char*)d_ws;

    uint2* staging = (uint2*)p;                 // [2E] pairs (dead after CSR build)
    float* z2      = (float*)p;                 // [N,64] f32 (layer 2, aliases staging)
    {
        size_t r0 = (size_t)twoE * sizeof(uint2);
        size_t r1 = (size_t)N * 64 * sizeof(float);
        p += (r0 > r1 ? r0 : r1);
    }
    unsigned short* m0  = (unsigned short*)p; p += nb128;  // [N,128] mean rel0 (t0/t1 reuse)
    unsigned short* m1  = (unsigned short*)p; p += nb128;  // [N,128] mean rel1 (h2b reuse)
    unsigned short* xb  = (unsigned short*)p; p += nb128;  // [N,128] bf16 x
    unsigned short* h1b = (unsigned short*)p; p += nb128;  // [N,128] bf16 h1
    unsigned short* WT1z = (unsigned short*)p; p += 16384 * 2;
    unsigned short* WT1a = (unsigned short*)p; p += 16384 * 2;
    unsigned short* WT1b = (unsigned short*)p; p += 16384 * 2;
    unsigned short* WT2z = (unsigned short*)p; p += 8192 * 2;
    unsigned short* WT2a = (unsigned short*)p; p += 8192 * 2;
    unsigned short* WT2b = (unsigned short*)p; p += 8192 * 2;
    float* bc1 = (float*)p; p += 128 * sizeof(float);
    float* bc2 = (float*)p; p += 64 * sizeof(float);
    int* bcnt = (int*)p; p += (size_t)2 * NBK_MAX * sizeof(int);
    int* gcur = (int*)p; p += (size_t)2 * NBK_MAX * sizeof(int);
    int* bko  = (int*)p; p += ((size_t)2 * NBK_MAX + 1) * sizeof(int);
    int* off  = (int*)p; p += (size_t)2 * N * sizeof(int);
    int* csr  = (int*)p;

    unsigned short* t0  = m0;                       // [N,64] bf16
    unsigned short* t1  = m0 + (size_t)N * 64;      // [N,64] bf16
    unsigned short* h2b = m1;                       // [N,64] bf16

    const int BS = 256;
    const int edge_blocks = (twoE + EPB - 1) / EPB;
    const int gx = (N + 63) / 64;

    // ---- CSR build (radix by dst bucket) ----
    hipMemsetAsync(bcnt, 0, (size_t)4 * NBK_MAX * sizeof(int), stream);
    bucket_count_kernel<<<edge_blocks, BS, 0, stream>>>(edges, bcnt, NBK, E);
    bucket_scan_kernel<<<1, 1024, 0, stream>>>(bcnt, bko, rbT, twoE);
    partition_kernel<<<edge_blocks, BS, 0, stream>>>(edges, bko, gcur, staging, NBK, E);
    bucket_csr_kernel<<<rbT, BS, 0, stream>>>(staging, bko, csr, off, NBK, N);

    // ---- prep ----
    cvt_kernel<<<(N * 32 + BS - 1) / BS, BS, 0, stream>>>(x, xb, N * 32);
    prep_kernel<<<(16384 + BS - 1) / BS, BS, 0, stream>>>(
        Ws1, Wn1, b1, Ws2, Wn2, b2,
        WT1z, WT1a, WT1b, bc1, WT2z, WT2a, WT2b, bc2);

    // ---- Layer 1: aggregate raw x, then fused 3-matmul GEMM + bias + relu
    agg1_kernel<<<(N + 3) / 4, BS, 0, stream>>>(xb, csr, off, m0, m1, N, twoE);
    gemm1_fused_kernel<<<gx, BS, 0, stream>>>(xb, m0, m1, WT1z, WT1a, WT1b,
                                              bc1, h1b, N);

    // ---- Layer 2: one fused transform (3 outputs), then aggregate ----
    gemm2_fused_kernel<<<gx, BS, 0, stream>>>(h1b, WT2z, WT2a, WT2b, bc2,
                                              z2, t0, t1, N);
    agg2_kernel<<<(N + 3) / 4, BS, 0, stream>>>(t0, t1, z2, csr, off, h2b, N, twoE);

    // ---- Scores (pos + neg in one launch) ----
    score_kernel<<<((E + En) * 8 + BS - 1) / BS, BS, 0, stream>>>(
        h2b, edges, neg, out, E, En);
}